// Round 4
// baseline (755.869 us; speedup 1.0000x reference)
//
#include <hip/hip_runtime.h>
#include <stdint.h>

typedef unsigned short ushort_t;

#define KK3 3
#define IC 32      // input capsules
#define IP 16      // input pose
#define OC 32      // output capsules
#define OP 16      // output pose
#define NI 288     // KK3*KK3*IC (im2col "i" dimension)
#define HH 12
#define WWW 12
#define NTOT 1152  // b*h*w
#define CQ 512     // OC*OP
#define EPSQ 1e-9f
#define RWAVES 16  // waves per route block (1024 threads)
#define RSTEPS 9   // i-steps per lane: NI / (RWAVES*2 i-rows per wave)

__device__ __forceinline__ float bf_lo(unsigned u) { return __uint_as_float(u << 16); }
__device__ __forceinline__ float bf_hi(unsigned u) { return __uint_as_float(u & 0xffff0000u); }
__device__ __forceinline__ ushort_t f2bf(float f) {
    unsigned u = __float_as_uint(f);
    return (ushort_t)((u + 0x7fffu + ((u >> 16) & 1u)) >> 16);   // RNE
}

// ---------------------------------------------------------------------------
// Kernel A: votes[nl][i][c][q] (bf16) for one pixel chunk.  (unchanged)
// grid = (NI, ceil(cnt/64)), block = 128.  thread t -> (c = t>>2, qq = t&3)
// ---------------------------------------------------------------------------
__global__ __launch_bounds__(128) void votes_kernel(
    const float* __restrict__ x, const float* __restrict__ Wg,
    ushort_t* __restrict__ votes, int nStart, int nCount)
{
    __shared__ float u_lds[64][IP];

    const int i = blockIdx.x;
    const int tileBase = blockIdx.y * 64;
    const int nC = min(64, nCount - tileBase);
    const int t = threadIdx.x;
    const int c = t >> 2;
    const int qq = t & 3;

    const int ky = i / (KK3 * IC);
    const int kx = (i / IC) % KK3;
    const int ic = i % IC;

    {
        const int nl = t >> 1;
        const int ph = (t & 1) * 8;
        if (nl < nC) {
            const int n = nStart + tileBase + nl;
            const int b = n / (HH * WWW);
            const int rem = n % (HH * WWW);
            const int y = rem / WWW;
            const int xx = rem % WWW;
            const int sy = y + ky - 1;
            const int sx = xx + kx - 1;
            float4 v0 = make_float4(0.f, 0.f, 0.f, 0.f), v1 = v0;
            if (sy >= 0 && sy < HH && sx >= 0 && sx < WWW) {
                const float* src = x + ((((size_t)b * HH + sy) * WWW + sx) * IC + ic) * IP + ph;
                v0 = *(const float4*)(src);
                v1 = *(const float4*)(src + 4);
            }
            *(float4*)&u_lds[nl][ph] = v0;
            *(float4*)&u_lds[nl][ph + 4] = v1;
        }
    }

    float4 w[IP];
    {
        const float* wb = Wg + ((size_t)i * OC + c) * (IP * OP) + qq * 4;
#pragma unroll
        for (int p = 0; p < IP; ++p) w[p] = *(const float4*)(wb + p * OP);
    }
    __syncthreads();

    ushort_t* vb = votes + ((size_t)tileBase * NI + i) * CQ + c * OP + qq * 4;
    for (int nl = 0; nl < nC; ++nl) {
        const float4 u0 = *(const float4*)&u_lds[nl][0];
        const float4 u1 = *(const float4*)&u_lds[nl][4];
        const float4 u2 = *(const float4*)&u_lds[nl][8];
        const float4 u3 = *(const float4*)&u_lds[nl][12];
        float a0 = 0.f, a1 = 0.f, a2 = 0.f, a3 = 0.f;
#define ACC(uf, pp)                                         \
        a0 = fmaf(uf, w[pp].x, a0); a1 = fmaf(uf, w[pp].y, a1); \
        a2 = fmaf(uf, w[pp].z, a2); a3 = fmaf(uf, w[pp].w, a3);
        ACC(u0.x, 0)  ACC(u0.y, 1)  ACC(u0.z, 2)  ACC(u0.w, 3)
        ACC(u1.x, 4)  ACC(u1.y, 5)  ACC(u1.z, 6)  ACC(u1.w, 7)
        ACC(u2.x, 8)  ACC(u2.y, 9)  ACC(u2.z, 10) ACC(u2.w, 11)
        ACC(u3.x, 12) ACC(u3.y, 13) ACC(u3.z, 14) ACC(u3.w, 15)
#undef ACC
        ushort4 st;
        st.x = f2bf(a0); st.y = f2bf(a1); st.z = f2bf(a2); st.w = f2bf(a3);
        *(ushort4*)vb = st;
        vb += (size_t)NI * CQ;
    }
}

// ---------------------------------------------------------------------------
// Kernel B: DR routing, votes register-resident, sized for the 128-VGPR cap.
// block = 1024 (16 waves), grid = cnt pixels.
// lane l: isub = l>>5 (which of 2 i-rows this wave handles per step),
//          c = l&31 (output capsule). Lane owns full 16-q vote row of
// i = isub + 2*wv + 32*r, r in [0,9): 9 x 2 uint4 = 72 VGPRs of bf16 votes.
// Agreement is in-lane (16 FMA); softmax over c = 5 shfl_xor in the 32-group;
// logits live in LDS (addr i*32+c -> lane c hits bank c, conflict-free).
// ---------------------------------------------------------------------------
#define UNPACK16(A, B)                                                     \
    const float f0 = bf_lo(A.x), f1 = bf_hi(A.x), f2 = bf_lo(A.y),         \
                f3 = bf_hi(A.y), f4 = bf_lo(A.z), f5 = bf_hi(A.z),         \
                f6 = bf_lo(A.w), f7 = bf_hi(A.w), f8 = bf_lo(B.x),         \
                f9 = bf_hi(B.x), f10 = bf_lo(B.y), f11 = bf_hi(B.y),       \
                f12 = bf_lo(B.z), f13 = bf_hi(B.z), f14 = bf_lo(B.w),      \
                f15 = bf_hi(B.w);

__global__ __launch_bounds__(1024) void route_kernel(
    const ushort_t* __restrict__ votes, const float* __restrict__ bias,
    float* __restrict__ out, int nStart)
{
    __shared__ float lg_lds[NI * OC];     // 36 KB logits
    __shared__ float sPart[RWAVES][CQ];   // 32 KB
    __shared__ float s_sh[CQ];
    __shared__ float v_sh[CQ];
    __shared__ float fac_sh[OC];

    const int bn = blockIdx.x;
    const int t = threadIdx.x;
    const int wv = t >> 6;        // 0..15
    const int l = t & 63;
    const int isub = l >> 5;      // 0 / 1
    const int c = l & 31;
    const int iBase = 2 * wv + isub;   // 0..31; lane's i = iBase + 32*r

    const ushort_t* pbase = votes + (size_t)bn * NI * CQ + (size_t)iBase * CQ + c * OP;

    // ---- load votes into registers (72 VGPRs)
    uint4 pa[RSTEPS], pb[RSTEPS];
#pragma unroll
    for (int r = 0; r < RSTEPS; ++r) {
        const uint4* p = (const uint4*)(pbase + (size_t)r * 32 * CQ);
        pa[r] = p[0];
        pb[r] = p[1];
    }

    // ---- iter 0: uniform coupling -> s0 = (sum_i votes)/OC + bias
    float sa[16];
#pragma unroll
    for (int q = 0; q < 16; ++q) sa[q] = 0.f;
#pragma unroll
    for (int r = 0; r < RSTEPS; ++r) {
        UNPACK16(pa[r], pb[r])
        sa[0] += f0;  sa[1] += f1;  sa[2] += f2;  sa[3] += f3;
        sa[4] += f4;  sa[5] += f5;  sa[6] += f6;  sa[7] += f7;
        sa[8] += f8;  sa[9] += f9;  sa[10] += f10; sa[11] += f11;
        sa[12] += f12; sa[13] += f13; sa[14] += f14; sa[15] += f15;
    }
#pragma unroll
    for (int q = 0; q < 16; ++q) sa[q] += __shfl_xor(sa[q], 32);
    if (isub == 0) {
#pragma unroll
        for (int k = 0; k < 4; ++k)
            *(float4*)&sPart[wv][c * 16 + 4 * k] = make_float4(sa[4*k], sa[4*k+1], sa[4*k+2], sa[4*k+3]);
    }

    float vr[16];
#pragma unroll
    for (int it = 0; it <= 2; ++it) {
        // ---- block reduce + squash (produces v_sh)
        __syncthreads();
        if (t < CQ) {
            float s = 0.f;
#pragma unroll
            for (int w = 0; w < RWAVES; ++w) s += sPart[w][t];
            s_sh[t] = fmaf(s, (it == 0) ? (1.0f / OC) : 1.0f, bias[t]);
        }
        __syncthreads();
        if (t < OC) {
            float sq = 0.f;
#pragma unroll
            for (int q = 0; q < OP; ++q) { const float s = s_sh[t * OP + q]; sq = fmaf(s, s, sq); }
            fac_sh[t] = (sq / (1.0f + sq)) * rsqrtf(sq + EPSQ);   // DR squash factor
        }
        __syncthreads();
        if (t < CQ) v_sh[t] = s_sh[t] * fac_sh[t >> 4];
        __syncthreads();
        if (it == 2) break;

        // ---- routed sweep: agreement -> logits -> softmax (no max-sub) -> s
#pragma unroll
        for (int k = 0; k < 4; ++k) {
            const float4 v4 = *(const float4*)&v_sh[c * 16 + 4 * k];
            vr[4*k] = v4.x; vr[4*k+1] = v4.y; vr[4*k+2] = v4.z; vr[4*k+3] = v4.w;
        }
#pragma unroll
        for (int q = 0; q < 16; ++q) sa[q] = 0.f;
#pragma unroll
        for (int r = 0; r < RSTEPS; ++r) {
            UNPACK16(pa[r], pb[r])
            float a = f0 * vr[0];
            a = fmaf(f1, vr[1], a);   a = fmaf(f2, vr[2], a);   a = fmaf(f3, vr[3], a);
            a = fmaf(f4, vr[4], a);   a = fmaf(f5, vr[5], a);   a = fmaf(f6, vr[6], a);
            a = fmaf(f7, vr[7], a);   a = fmaf(f8, vr[8], a);   a = fmaf(f9, vr[9], a);
            a = fmaf(f10, vr[10], a); a = fmaf(f11, vr[11], a); a = fmaf(f12, vr[12], a);
            a = fmaf(f13, vr[13], a); a = fmaf(f14, vr[14], a); a = fmaf(f15, vr[15], a);
            const int li = (iBase + 32 * r) * OC + c;
            if (it == 0) lg_lds[li] = a;           // logits after iter 0
            else          a += lg_lds[li];          // accumulated logits
            // softmax over 32 output caps (lane bits 0..4); |a| <= ~2 so the
            // max-subtraction is unnecessary (exp can't overflow)
            const float e = __expf(a);
            float es = e;
            es += __shfl_xor(es, 1);
            es += __shfl_xor(es, 2);
            es += __shfl_xor(es, 4);
            es += __shfl_xor(es, 8);
            es += __shfl_xor(es, 16);
            const float coup = __fdividef(e, es);
            sa[0] = fmaf(coup, f0, sa[0]);   sa[1] = fmaf(coup, f1, sa[1]);
            sa[2] = fmaf(coup, f2, sa[2]);   sa[3] = fmaf(coup, f3, sa[3]);
            sa[4] = fmaf(coup, f4, sa[4]);   sa[5] = fmaf(coup, f5, sa[5]);
            sa[6] = fmaf(coup, f6, sa[6]);   sa[7] = fmaf(coup, f7, sa[7]);
            sa[8] = fmaf(coup, f8, sa[8]);   sa[9] = fmaf(coup, f9, sa[9]);
            sa[10] = fmaf(coup, f10, sa[10]); sa[11] = fmaf(coup, f11, sa[11]);
            sa[12] = fmaf(coup, f12, sa[12]); sa[13] = fmaf(coup, f13, sa[13]);
            sa[14] = fmaf(coup, f14, sa[14]); sa[15] = fmaf(coup, f15, sa[15]);
        }
#pragma unroll
        for (int q = 0; q < 16; ++q) sa[q] += __shfl_xor(sa[q], 32);
        if (isub == 0) {
#pragma unroll
            for (int k = 0; k < 4; ++k)
                *(float4*)&sPart[wv][c * 16 + 4 * k] = make_float4(sa[4*k], sa[4*k+1], sa[4*k+2], sa[4*k+3]);
        }
    }

    if (t < CQ) out[(size_t)(nStart + bn) * CQ + t] = v_sh[t];
}

// ---------------------------------------------------------------------------
extern "C" void kernel_launch(void* const* d_in, const int* in_sizes, int n_in,
                              void* d_out, int out_size, void* d_ws, size_t ws_size,
                              hipStream_t stream)
{
    const float* x = (const float*)d_in[0];
    const float* Wg = (const float*)d_in[1];
    const float* bias = (const float*)d_in[2];
    float* out = (float*)d_out;
    ushort_t* votes = (ushort_t*)d_ws;

    const size_t perN = (size_t)NI * CQ * sizeof(ushort_t);  // 294912 B per pixel
    size_t fit = ws_size / perN;
    int chunk = (fit >= 384) ? 384 : (int)fit;   // 384-pixel chunk = 113 MB, L3-resident
    if (chunk < 1) chunk = 1;

    for (int start = 0; start < NTOT; start += chunk) {
        const int cnt = (NTOT - start < chunk) ? (NTOT - start) : chunk;
        dim3 gA(NI, (cnt + 63) / 64);
        hipLaunchKernelGGL(votes_kernel, gA, dim3(128), 0, stream, x, Wg, votes, start, cnt);
        hipLaunchKernelGGL(route_kernel, dim3(cnt), dim3(1024), 0, stream, votes, bias, out, start);
    }
}

// Round 5
// 711.635 us; speedup vs baseline: 1.0622x; 1.0622x over previous
//
#include <hip/hip_runtime.h>
#include <stdint.h>

typedef unsigned short ushort_t;

#define KK3 3
#define IC 32      // input capsules
#define IP 16      // input pose
#define OC 32      // output capsules
#define OP 16      // output pose
#define NI 288     // KK3*KK3*IC (im2col "i" dimension)
#define HH 12
#define WWW 12
#define NTOT 1152  // b*h*w
#define CQ 512     // OC*OP
#define EPSQ 1e-9f
#define RWAVES 16  // waves per route block (1024 threads)
#define RSTEPS 9   // i-steps per lane: NI / (RWAVES*2 i-rows per wave)

__device__ __forceinline__ float bf_lo(unsigned u) { return __uint_as_float(u << 16); }
__device__ __forceinline__ float bf_hi(unsigned u) { return __uint_as_float(u & 0xffff0000u); }
__device__ __forceinline__ ushort_t f2bf(float f) {
    unsigned u = __float_as_uint(f);
    return (ushort_t)((u + 0x7fffu + ((u >> 16) & 1u)) >> 16);   // RNE
}

// ---------------------------------------------------------------------------
// Kernel A: votes[nl][i][c][q] (bf16) for one pixel chunk.  (unchanged)
// grid = (NI, ceil(cnt/64)), block = 128.  thread t -> (c = t>>2, qq = t&3)
// ---------------------------------------------------------------------------
__global__ __launch_bounds__(128) void votes_kernel(
    const float* __restrict__ x, const float* __restrict__ Wg,
    ushort_t* __restrict__ votes, int nStart, int nCount)
{
    __shared__ float u_lds[64][IP];

    const int i = blockIdx.x;
    const int tileBase = blockIdx.y * 64;
    const int nC = min(64, nCount - tileBase);
    const int t = threadIdx.x;
    const int c = t >> 2;
    const int qq = t & 3;

    const int ky = i / (KK3 * IC);
    const int kx = (i / IC) % KK3;
    const int ic = i % IC;

    {
        const int nl = t >> 1;
        const int ph = (t & 1) * 8;
        if (nl < nC) {
            const int n = nStart + tileBase + nl;
            const int b = n / (HH * WWW);
            const int rem = n % (HH * WWW);
            const int y = rem / WWW;
            const int xx = rem % WWW;
            const int sy = y + ky - 1;
            const int sx = xx + kx - 1;
            float4 v0 = make_float4(0.f, 0.f, 0.f, 0.f), v1 = v0;
            if (sy >= 0 && sy < HH && sx >= 0 && sx < WWW) {
                const float* src = x + ((((size_t)b * HH + sy) * WWW + sx) * IC + ic) * IP + ph;
                v0 = *(const float4*)(src);
                v1 = *(const float4*)(src + 4);
            }
            *(float4*)&u_lds[nl][ph] = v0;
            *(float4*)&u_lds[nl][ph + 4] = v1;
        }
    }

    float4 w[IP];
    {
        const float* wb = Wg + ((size_t)i * OC + c) * (IP * OP) + qq * 4;
#pragma unroll
        for (int p = 0; p < IP; ++p) w[p] = *(const float4*)(wb + p * OP);
    }
    __syncthreads();

    ushort_t* vb = votes + ((size_t)tileBase * NI + i) * CQ + c * OP + qq * 4;
    for (int nl = 0; nl < nC; ++nl) {
        const float4 u0 = *(const float4*)&u_lds[nl][0];
        const float4 u1 = *(const float4*)&u_lds[nl][4];
        const float4 u2 = *(const float4*)&u_lds[nl][8];
        const float4 u3 = *(const float4*)&u_lds[nl][12];
        float a0 = 0.f, a1 = 0.f, a2 = 0.f, a3 = 0.f;
#define ACC(uf, pp)                                         \
        a0 = fmaf(uf, w[pp].x, a0); a1 = fmaf(uf, w[pp].y, a1); \
        a2 = fmaf(uf, w[pp].z, a2); a3 = fmaf(uf, w[pp].w, a3);
        ACC(u0.x, 0)  ACC(u0.y, 1)  ACC(u0.z, 2)  ACC(u0.w, 3)
        ACC(u1.x, 4)  ACC(u1.y, 5)  ACC(u1.z, 6)  ACC(u1.w, 7)
        ACC(u2.x, 8)  ACC(u2.y, 9)  ACC(u2.z, 10) ACC(u2.w, 11)
        ACC(u3.x, 12) ACC(u3.y, 13) ACC(u3.z, 14) ACC(u3.w, 15)
#undef ACC
        ushort4 st;
        st.x = f2bf(a0); st.y = f2bf(a1); st.z = f2bf(a2); st.w = f2bf(a3);
        *(ushort4*)vb = st;
        vb += (size_t)NI * CQ;
    }
}

// ---------------------------------------------------------------------------
// Kernel B: DR routing, votes register-resident, sized for the 128-VGPR cap.
// block = 1024 (16 waves), grid = cnt pixels.
// lane l: isub = l>>5, c = l&31. Lane owns full 16-q vote row of
// i = isub + 2*wv + 32*r, r in [0,9): 9 x 2 uint4 = 72 VGPRs of bf16 votes.
// Live regs ~105 < 128 (hard cap for 1024-thread block: 512 VGPR file / 4
// waves per SIMD). amdgpu_waves_per_eu(4,4) pins occupancy at 1 block/CU so
// the allocator budgets the full 128 instead of targeting 64 (R4 spilled:
// LDS 74 KB allowed 2 blocks/CU -> 8 waves/EU -> 64-VGPR target -> 600 MB of
// scratch traffic). LDS padded to ~84 KB so 2 blocks/CU is also LDS-illegal.
// ---------------------------------------------------------------------------
#define UNPACK16(A, B)                                                     \
    const float f0 = bf_lo(A.x), f1 = bf_hi(A.x), f2 = bf_lo(A.y),         \
                f3 = bf_hi(A.y), f4 = bf_lo(A.z), f5 = bf_hi(A.z),         \
                f6 = bf_lo(A.w), f7 = bf_hi(A.w), f8 = bf_lo(B.x),         \
                f9 = bf_hi(B.x), f10 = bf_lo(B.y), f11 = bf_hi(B.y),       \
                f12 = bf_lo(B.z), f13 = bf_hi(B.z), f14 = bf_lo(B.w),      \
                f15 = bf_hi(B.w);

__global__ __attribute__((amdgpu_waves_per_eu(4, 4))) __launch_bounds__(1024)
void route_kernel(
    const ushort_t* __restrict__ votes, const float* __restrict__ bias,
    float* __restrict__ out, int nStart)
{
    __shared__ float lg_lds[NI * OC];     // 36 KB logits
    __shared__ float sPart[RWAVES][CQ];   // 32 KB
    __shared__ float s_sh[CQ];
    __shared__ float v_sh[CQ];
    __shared__ float fac_sh[OC];
    __shared__ float pad_lds[2560];       // ~10 KB: push LDS > 80 KB so a
                                          // second block/CU can never fit

    const int bn = blockIdx.x;
    const int t = threadIdx.x;
    ((volatile float*)pad_lds)[t & 2047] = 0.f;   // keep pad allocated

    const int wv = t >> 6;        // 0..15
    const int l = t & 63;
    const int isub = l >> 5;      // 0 / 1
    const int c = l & 31;
    const int iBase = 2 * wv + isub;   // 0..31; lane's i = iBase + 32*r

    const ushort_t* pbase = votes + (size_t)bn * NI * CQ + (size_t)iBase * CQ + c * OP;

    // ---- load votes into registers (72 VGPRs)
    uint4 pa[RSTEPS], pb[RSTEPS];
#pragma unroll
    for (int r = 0; r < RSTEPS; ++r) {
        const uint4* p = (const uint4*)(pbase + (size_t)r * 32 * CQ);
        pa[r] = p[0];
        pb[r] = p[1];
    }

    // ---- iter 0: uniform coupling -> s0 = (sum_i votes)/OC + bias
    float sa[16];
#pragma unroll
    for (int q = 0; q < 16; ++q) sa[q] = 0.f;
#pragma unroll
    for (int r = 0; r < RSTEPS; ++r) {
        UNPACK16(pa[r], pb[r])
        sa[0] += f0;  sa[1] += f1;  sa[2] += f2;  sa[3] += f3;
        sa[4] += f4;  sa[5] += f5;  sa[6] += f6;  sa[7] += f7;
        sa[8] += f8;  sa[9] += f9;  sa[10] += f10; sa[11] += f11;
        sa[12] += f12; sa[13] += f13; sa[14] += f14; sa[15] += f15;
    }
#pragma unroll
    for (int q = 0; q < 16; ++q) sa[q] += __shfl_xor(sa[q], 32);
    if (isub == 0) {
#pragma unroll
        for (int k = 0; k < 4; ++k)
            *(float4*)&sPart[wv][c * 16 + 4 * k] = make_float4(sa[4*k], sa[4*k+1], sa[4*k+2], sa[4*k+3]);
    }

    float vr[16];
#pragma unroll
    for (int it = 0; it <= 2; ++it) {
        // ---- block reduce + squash (produces v_sh)
        __syncthreads();
        if (t < CQ) {
            float s = 0.f;
#pragma unroll
            for (int w = 0; w < RWAVES; ++w) s += sPart[w][t];
            s_sh[t] = fmaf(s, (it == 0) ? (1.0f / OC) : 1.0f, bias[t]);
        }
        __syncthreads();
        if (t < OC) {
            float sq = 0.f;
#pragma unroll
            for (int q = 0; q < OP; ++q) { const float s = s_sh[t * OP + q]; sq = fmaf(s, s, sq); }
            fac_sh[t] = (sq / (1.0f + sq)) * rsqrtf(sq + EPSQ);   // DR squash factor
        }
        __syncthreads();
        if (t < CQ) v_sh[t] = s_sh[t] * fac_sh[t >> 4];
        __syncthreads();
        if (it == 2) break;

        // ---- routed sweep: agreement -> logits -> softmax (no max-sub) -> s
#pragma unroll
        for (int k = 0; k < 4; ++k) {
            const float4 v4 = *(const float4*)&v_sh[c * 16 + 4 * k];
            vr[4*k] = v4.x; vr[4*k+1] = v4.y; vr[4*k+2] = v4.z; vr[4*k+3] = v4.w;
        }
#pragma unroll
        for (int q = 0; q < 16; ++q) sa[q] = 0.f;
#pragma unroll
        for (int r = 0; r < RSTEPS; ++r) {
            UNPACK16(pa[r], pb[r])
            float a = f0 * vr[0];
            a = fmaf(f1, vr[1], a);   a = fmaf(f2, vr[2], a);   a = fmaf(f3, vr[3], a);
            a = fmaf(f4, vr[4], a);   a = fmaf(f5, vr[5], a);   a = fmaf(f6, vr[6], a);
            a = fmaf(f7, vr[7], a);   a = fmaf(f8, vr[8], a);   a = fmaf(f9, vr[9], a);
            a = fmaf(f10, vr[10], a); a = fmaf(f11, vr[11], a); a = fmaf(f12, vr[12], a);
            a = fmaf(f13, vr[13], a); a = fmaf(f14, vr[14], a); a = fmaf(f15, vr[15], a);
            const int li = (iBase + 32 * r) * OC + c;
            if (it == 0) lg_lds[li] = a;           // logits after iter 0
            else          a += lg_lds[li];          // accumulated logits
            // softmax over 32 output caps (lane bits 0..4); |a| <= ~2 so the
            // max-subtraction is unnecessary (exp can't overflow)
            const float e = __expf(a);
            float es = e;
            es += __shfl_xor(es, 1);
            es += __shfl_xor(es, 2);
            es += __shfl_xor(es, 4);
            es += __shfl_xor(es, 8);
            es += __shfl_xor(es, 16);
            const float coup = __fdividef(e, es);
            sa[0] = fmaf(coup, f0, sa[0]);   sa[1] = fmaf(coup, f1, sa[1]);
            sa[2] = fmaf(coup, f2, sa[2]);   sa[3] = fmaf(coup, f3, sa[3]);
            sa[4] = fmaf(coup, f4, sa[4]);   sa[5] = fmaf(coup, f5, sa[5]);
            sa[6] = fmaf(coup, f6, sa[6]);   sa[7] = fmaf(coup, f7, sa[7]);
            sa[8] = fmaf(coup, f8, sa[8]);   sa[9] = fmaf(coup, f9, sa[9]);
            sa[10] = fmaf(coup, f10, sa[10]); sa[11] = fmaf(coup, f11, sa[11]);
            sa[12] = fmaf(coup, f12, sa[12]); sa[13] = fmaf(coup, f13, sa[13]);
            sa[14] = fmaf(coup, f14, sa[14]); sa[15] = fmaf(coup, f15, sa[15]);
        }
#pragma unroll
        for (int q = 0; q < 16; ++q) sa[q] += __shfl_xor(sa[q], 32);
        if (isub == 0) {
#pragma unroll
            for (int k = 0; k < 4; ++k)
                *(float4*)&sPart[wv][c * 16 + 4 * k] = make_float4(sa[4*k], sa[4*k+1], sa[4*k+2], sa[4*k+3]);
        }
    }

    if (t < CQ) out[(size_t)(nStart + bn) * CQ + t] = v_sh[t];
}

// ---------------------------------------------------------------------------
extern "C" void kernel_launch(void* const* d_in, const int* in_sizes, int n_in,
                              void* d_out, int out_size, void* d_ws, size_t ws_size,
                              hipStream_t stream)
{
    const float* x = (const float*)d_in[0];
    const float* Wg = (const float*)d_in[1];
    const float* bias = (const float*)d_in[2];
    float* out = (float*)d_out;
    ushort_t* votes = (ushort_t*)d_ws;

    const size_t perN = (size_t)NI * CQ * sizeof(ushort_t);  // 294912 B per pixel
    size_t fit = ws_size / perN;
    int chunk = (fit >= NTOT) ? NTOT : (int)fit;  // votes read once now; no L3-chunking needed
    if (chunk < 1) chunk = 1;

    for (int start = 0; start < NTOT; start += chunk) {
        const int cnt = (NTOT - start < chunk) ? (NTOT - start) : chunk;
        dim3 gA(NI, (cnt + 63) / 64);
        hipLaunchKernelGGL(votes_kernel, gA, dim3(128), 0, stream, x, Wg, votes, start, cnt);
        hipLaunchKernelGGL(route_kernel, dim3(cnt), dim3(1024), 0, stream, votes, bias, out, start);
    }
}

// Round 6
// 625.829 us; speedup vs baseline: 1.2078x; 1.1371x over previous
//
#include <hip/hip_runtime.h>
#include <stdint.h>

typedef unsigned short ushort_t;

#define KK3 3
#define IC 32      // input capsules
#define IP 16      // input pose
#define OC 32      // output capsules
#define OP 16      // output pose
#define NI 288     // KK3*KK3*IC (im2col "i" dimension)
#define HH 12
#define WWW 12
#define NTOT 1152  // b*h*w
#define CQ 512     // OC*OP
#define EPSQ 1e-9f
#define RWAVES 16  // waves per route block (1024 threads)
#define RSTEPS 9   // i-steps per lane: NI / 32 i-rows handled per step

__device__ __forceinline__ float bf_lo(unsigned u) { return __uint_as_float(u << 16); }
__device__ __forceinline__ float bf_hi(unsigned u) { return __uint_as_float(u & 0xffff0000u); }
__device__ __forceinline__ ushort_t f2bf(float f) {
    unsigned u = __float_as_uint(f);
    return (ushort_t)((u + 0x7fffu + ((u >> 16) & 1u)) >> 16);   // RNE
}

// ---------------------------------------------------------------------------
// Kernel A: votes[nl][i][c][q] (bf16) for one pixel chunk.  (unchanged)
// grid = (NI, ceil(cnt/64)), block = 128.  thread t -> (c = t>>2, qq = t&3)
// ---------------------------------------------------------------------------
__global__ __launch_bounds__(128) void votes_kernel(
    const float* __restrict__ x, const float* __restrict__ Wg,
    ushort_t* __restrict__ votes, int nStart, int nCount)
{
    __shared__ float u_lds[64][IP];

    const int i = blockIdx.x;
    const int tileBase = blockIdx.y * 64;
    const int nC = min(64, nCount - tileBase);
    const int t = threadIdx.x;
    const int c = t >> 2;
    const int qq = t & 3;

    const int ky = i / (KK3 * IC);
    const int kx = (i / IC) % KK3;
    const int ic = i % IC;

    {
        const int nl = t >> 1;
        const int ph = (t & 1) * 8;
        if (nl < nC) {
            const int n = nStart + tileBase + nl;
            const int b = n / (HH * WWW);
            const int rem = n % (HH * WWW);
            const int y = rem / WWW;
            const int xx = rem % WWW;
            const int sy = y + ky - 1;
            const int sx = xx + kx - 1;
            float4 v0 = make_float4(0.f, 0.f, 0.f, 0.f), v1 = v0;
            if (sy >= 0 && sy < HH && sx >= 0 && sx < WWW) {
                const float* src = x + ((((size_t)b * HH + sy) * WWW + sx) * IC + ic) * IP + ph;
                v0 = *(const float4*)(src);
                v1 = *(const float4*)(src + 4);
            }
            *(float4*)&u_lds[nl][ph] = v0;
            *(float4*)&u_lds[nl][ph + 4] = v1;
        }
    }

    float4 w[IP];
    {
        const float* wb = Wg + ((size_t)i * OC + c) * (IP * OP) + qq * 4;
#pragma unroll
        for (int p = 0; p < IP; ++p) w[p] = *(const float4*)(wb + p * OP);
    }
    __syncthreads();

    ushort_t* vb = votes + ((size_t)tileBase * NI + i) * CQ + c * OP + qq * 4;
    for (int nl = 0; nl < nC; ++nl) {
        const float4 u0 = *(const float4*)&u_lds[nl][0];
        const float4 u1 = *(const float4*)&u_lds[nl][4];
        const float4 u2 = *(const float4*)&u_lds[nl][8];
        const float4 u3 = *(const float4*)&u_lds[nl][12];
        float a0 = 0.f, a1 = 0.f, a2 = 0.f, a3 = 0.f;
#define ACC(uf, pp)                                         \
        a0 = fmaf(uf, w[pp].x, a0); a1 = fmaf(uf, w[pp].y, a1); \
        a2 = fmaf(uf, w[pp].z, a2); a3 = fmaf(uf, w[pp].w, a3);
        ACC(u0.x, 0)  ACC(u0.y, 1)  ACC(u0.z, 2)  ACC(u0.w, 3)
        ACC(u1.x, 4)  ACC(u1.y, 5)  ACC(u1.z, 6)  ACC(u1.w, 7)
        ACC(u2.x, 8)  ACC(u2.y, 9)  ACC(u2.z, 10) ACC(u2.w, 11)
        ACC(u3.x, 12) ACC(u3.y, 13) ACC(u3.z, 14) ACC(u3.w, 15)
#undef ACC
        ushort4 st;
        st.x = f2bf(a0); st.y = f2bf(a1); st.z = f2bf(a2); st.w = f2bf(a3);
        *(ushort4*)vb = st;
        vb += (size_t)NI * CQ;
    }
}

// ---------------------------------------------------------------------------
// Kernel B: DR routing, STREAMING votes (3 passes over L3-resident votes).
// Designed for the 64-VGPR budget the allocator actually gives 1024-thread
// blocks (R2/R4/R5 all spilled trying to hold votes in registers; streaming
// keeps ~55 live VGPRs). block = 1024 (16 waves), grid = cnt pixels.
// lane l: isub = l>>5, c = l&31. Lane handles full 16-q vote row of
// i = (2*wv + isub) + 32*r, r in [0,9), loaded as 2 x uint4 per step and
// consumed immediately. Agreement in-lane; softmax = 5 shfl_xor over the
// 32-lane c-group; logits in LDS (addr i*32+c -> 2-way conflict = free).
// LDS 72 KB -> 2 blocks/CU -> 32 waves/CU (full occupancy).
// ---------------------------------------------------------------------------
#define UNPACK16(A, B)                                                     \
    const float f0 = bf_lo(A.x), f1 = bf_hi(A.x), f2 = bf_lo(A.y),         \
                f3 = bf_hi(A.y), f4 = bf_lo(A.z), f5 = bf_hi(A.z),         \
                f6 = bf_lo(A.w), f7 = bf_hi(A.w), f8 = bf_lo(B.x),         \
                f9 = bf_hi(B.x), f10 = bf_lo(B.y), f11 = bf_hi(B.y),       \
                f12 = bf_lo(B.z), f13 = bf_hi(B.z), f14 = bf_lo(B.w),      \
                f15 = bf_hi(B.w);

__global__ __launch_bounds__(1024) void route_kernel(
    const ushort_t* __restrict__ votes, const float* __restrict__ bias,
    float* __restrict__ out, int nStart)
{
    __shared__ float lg_lds[NI * OC];     // 36 KB logits
    __shared__ float sPart[RWAVES][CQ];   // 32 KB
    __shared__ float s_sh[CQ];
    __shared__ float v_sh[CQ];
    __shared__ float fac_sh[OC];

    const int bn = blockIdx.x;
    const int t = threadIdx.x;
    const int wv = t >> 6;        // 0..15
    const int l = t & 63;
    const int isub = l >> 5;      // 0 / 1
    const int c = l & 31;
    const int iBase = 2 * wv + isub;   // 0..31; lane's i = iBase + 32*r

    const ushort_t* pbase = votes + (size_t)bn * NI * CQ + (size_t)iBase * CQ + c * OP;

    float sa[16];

    // ---- iter 0 sweep: uniform coupling -> s0 = (sum_i votes)/OC + bias
#pragma unroll
    for (int q = 0; q < 16; ++q) sa[q] = 0.f;
    for (int r = 0; r < RSTEPS; ++r) {
        const uint4* p = (const uint4*)(pbase + (size_t)r * 32 * CQ);
        const uint4 A = p[0];
        const uint4 B = p[1];
        UNPACK16(A, B)
        sa[0] += f0;  sa[1] += f1;  sa[2] += f2;  sa[3] += f3;
        sa[4] += f4;  sa[5] += f5;  sa[6] += f6;  sa[7] += f7;
        sa[8] += f8;  sa[9] += f9;  sa[10] += f10; sa[11] += f11;
        sa[12] += f12; sa[13] += f13; sa[14] += f14; sa[15] += f15;
    }
#pragma unroll
    for (int q = 0; q < 16; ++q) sa[q] += __shfl_xor(sa[q], 32);
    if (isub == 0) {
#pragma unroll
        for (int k = 0; k < 4; ++k)
            *(float4*)&sPart[wv][c * 16 + 4 * k] = make_float4(sa[4*k], sa[4*k+1], sa[4*k+2], sa[4*k+3]);
    }

    float vr[16];
#pragma unroll
    for (int it = 0; it <= 2; ++it) {
        // ---- block reduce + squash (produces v_sh)
        __syncthreads();
        if (t < CQ) {
            float s = 0.f;
#pragma unroll
            for (int w = 0; w < RWAVES; ++w) s += sPart[w][t];
            s_sh[t] = fmaf(s, (it == 0) ? (1.0f / OC) : 1.0f, bias[t]);
        }
        __syncthreads();
        if (t < OC) {
            float sq = 0.f;
#pragma unroll
            for (int q = 0; q < OP; ++q) { const float s = s_sh[t * OP + q]; sq = fmaf(s, s, sq); }
            fac_sh[t] = (sq / (1.0f + sq)) * rsqrtf(sq + EPSQ);   // DR squash factor
        }
        __syncthreads();
        if (t < CQ) v_sh[t] = s_sh[t] * fac_sh[t >> 4];
        __syncthreads();
        if (it == 2) break;

        // ---- routed sweep (streaming): agreement -> logits -> softmax -> s
#pragma unroll
        for (int k = 0; k < 4; ++k) {
            const float4 v4 = *(const float4*)&v_sh[c * 16 + 4 * k];
            vr[4*k] = v4.x; vr[4*k+1] = v4.y; vr[4*k+2] = v4.z; vr[4*k+3] = v4.w;
        }
#pragma unroll
        for (int q = 0; q < 16; ++q) sa[q] = 0.f;
        for (int r = 0; r < RSTEPS; ++r) {
            const uint4* p = (const uint4*)(pbase + (size_t)r * 32 * CQ);
            const uint4 A = p[0];
            const uint4 B = p[1];
            UNPACK16(A, B)
            float a = f0 * vr[0];
            a = fmaf(f1, vr[1], a);   a = fmaf(f2, vr[2], a);   a = fmaf(f3, vr[3], a);
            a = fmaf(f4, vr[4], a);   a = fmaf(f5, vr[5], a);   a = fmaf(f6, vr[6], a);
            a = fmaf(f7, vr[7], a);   a = fmaf(f8, vr[8], a);   a = fmaf(f9, vr[9], a);
            a = fmaf(f10, vr[10], a); a = fmaf(f11, vr[11], a); a = fmaf(f12, vr[12], a);
            a = fmaf(f13, vr[13], a); a = fmaf(f14, vr[14], a); a = fmaf(f15, vr[15], a);
            const int li = (iBase + 32 * r) * OC + c;
            if (it == 0) lg_lds[li] = a;           // logits after iter 0
            else          a += lg_lds[li];          // accumulated logits
            // softmax over 32 output caps (lane bits 0..4); |a| <= ~2 so the
            // max-subtraction is unnecessary (exp can't overflow)
            const float e = __expf(a);
            float es = e;
            es += __shfl_xor(es, 1);
            es += __shfl_xor(es, 2);
            es += __shfl_xor(es, 4);
            es += __shfl_xor(es, 8);
            es += __shfl_xor(es, 16);
            const float coup = __fdividef(e, es);
            sa[0] = fmaf(coup, f0, sa[0]);   sa[1] = fmaf(coup, f1, sa[1]);
            sa[2] = fmaf(coup, f2, sa[2]);   sa[3] = fmaf(coup, f3, sa[3]);
            sa[4] = fmaf(coup, f4, sa[4]);   sa[5] = fmaf(coup, f5, sa[5]);
            sa[6] = fmaf(coup, f6, sa[6]);   sa[7] = fmaf(coup, f7, sa[7]);
            sa[8] = fmaf(coup, f8, sa[8]);   sa[9] = fmaf(coup, f9, sa[9]);
            sa[10] = fmaf(coup, f10, sa[10]); sa[11] = fmaf(coup, f11, sa[11]);
            sa[12] = fmaf(coup, f12, sa[12]); sa[13] = fmaf(coup, f13, sa[13]);
            sa[14] = fmaf(coup, f14, sa[14]); sa[15] = fmaf(coup, f15, sa[15]);
        }
#pragma unroll
        for (int q = 0; q < 16; ++q) sa[q] += __shfl_xor(sa[q], 32);
        if (isub == 0) {
#pragma unroll
            for (int k = 0; k < 4; ++k)
                *(float4*)&sPart[wv][c * 16 + 4 * k] = make_float4(sa[4*k], sa[4*k+1], sa[4*k+2], sa[4*k+3]);
        }
    }

    if (t < CQ) out[(size_t)(nStart + bn) * CQ + t] = v_sh[t];
}

// ---------------------------------------------------------------------------
extern "C" void kernel_launch(void* const* d_in, const int* in_sizes, int n_in,
                              void* d_out, int out_size, void* d_ws, size_t ws_size,
                              hipStream_t stream)
{
    const float* x = (const float*)d_in[0];
    const float* Wg = (const float*)d_in[1];
    const float* bias = (const float*)d_in[2];
    float* out = (float*)d_out;
    ushort_t* votes = (ushort_t*)d_ws;

    const size_t perN = (size_t)NI * CQ * sizeof(ushort_t);  // 294912 B per pixel
    size_t fit = ws_size / perN;
    int chunk = (fit >= 384) ? 384 : (int)fit;   // 113 MB votes chunk, L3-resident
    if (chunk < 1) chunk = 1;

    for (int start = 0; start < NTOT; start += chunk) {
        const int cnt = (NTOT - start < chunk) ? (NTOT - start) : chunk;
        dim3 gA(NI, (cnt + 63) / 64);
        hipLaunchKernelGGL(votes_kernel, gA, dim3(128), 0, stream, x, Wg, votes, start, cnt);
        hipLaunchKernelGGL(route_kernel, dim3(cnt), dim3(1024), 0, stream, votes, bias, out, start);
    }
}

// Round 7
// 259.876 us; speedup vs baseline: 2.9086x; 2.4082x over previous
//
#include <hip/hip_runtime.h>
#include <stdint.h>

typedef unsigned short ushort_t;

#define KK3 3
#define IC 32      // input capsules
#define IP 16      // input pose
#define OC 32      // output capsules
#define OP 16      // output pose
#define NI 288     // KK3*KK3*IC (im2col "i" dimension)
#define HH 12
#define WWW 12
#define NTOT 1152  // b*h*w
#define CQ 512     // OC*OP
#define EPSQ 1e-9f
#define RWAVES 4   // waves per route block (256 threads)
#define RSTEPS 36  // i-steps per lane: NI / 8 i-rows in flight per step

__device__ __forceinline__ float bf_lo(unsigned u) { return __uint_as_float(u << 16); }
__device__ __forceinline__ float bf_hi(unsigned u) { return __uint_as_float(u & 0xffff0000u); }
__device__ __forceinline__ ushort_t f2bf(float f) {
    unsigned u = __float_as_uint(f);
    return (ushort_t)((u + 0x7fffu + ((u >> 16) & 1u)) >> 16);   // RNE
}

// ---------------------------------------------------------------------------
// Kernel A: votes[nl][i][c][q] (bf16) for one pixel chunk.  (unchanged)
// grid = (NI, ceil(cnt/64)), block = 128.  thread t -> (c = t>>2, qq = t&3)
// ---------------------------------------------------------------------------
__global__ __launch_bounds__(128) void votes_kernel(
    const float* __restrict__ x, const float* __restrict__ Wg,
    ushort_t* __restrict__ votes, int nStart, int nCount)
{
    __shared__ float u_lds[64][IP];

    const int i = blockIdx.x;
    const int tileBase = blockIdx.y * 64;
    const int nC = min(64, nCount - tileBase);
    const int t = threadIdx.x;
    const int c = t >> 2;
    const int qq = t & 3;

    const int ky = i / (KK3 * IC);
    const int kx = (i / IC) % KK3;
    const int ic = i % IC;

    {
        const int nl = t >> 1;
        const int ph = (t & 1) * 8;
        if (nl < nC) {
            const int n = nStart + tileBase + nl;
            const int b = n / (HH * WWW);
            const int rem = n % (HH * WWW);
            const int y = rem / WWW;
            const int xx = rem % WWW;
            const int sy = y + ky - 1;
            const int sx = xx + kx - 1;
            float4 v0 = make_float4(0.f, 0.f, 0.f, 0.f), v1 = v0;
            if (sy >= 0 && sy < HH && sx >= 0 && sx < WWW) {
                const float* src = x + ((((size_t)b * HH + sy) * WWW + sx) * IC + ic) * IP + ph;
                v0 = *(const float4*)(src);
                v1 = *(const float4*)(src + 4);
            }
            *(float4*)&u_lds[nl][ph] = v0;
            *(float4*)&u_lds[nl][ph + 4] = v1;
        }
    }

    float4 w[IP];
    {
        const float* wb = Wg + ((size_t)i * OC + c) * (IP * OP) + qq * 4;
#pragma unroll
        for (int p = 0; p < IP; ++p) w[p] = *(const float4*)(wb + p * OP);
    }
    __syncthreads();

    ushort_t* vb = votes + ((size_t)tileBase * NI + i) * CQ + c * OP + qq * 4;
    for (int nl = 0; nl < nC; ++nl) {
        const float4 u0 = *(const float4*)&u_lds[nl][0];
        const float4 u1 = *(const float4*)&u_lds[nl][4];
        const float4 u2 = *(const float4*)&u_lds[nl][8];
        const float4 u3 = *(const float4*)&u_lds[nl][12];
        float a0 = 0.f, a1 = 0.f, a2 = 0.f, a3 = 0.f;
#define ACC(uf, pp)                                         \
        a0 = fmaf(uf, w[pp].x, a0); a1 = fmaf(uf, w[pp].y, a1); \
        a2 = fmaf(uf, w[pp].z, a2); a3 = fmaf(uf, w[pp].w, a3);
        ACC(u0.x, 0)  ACC(u0.y, 1)  ACC(u0.z, 2)  ACC(u0.w, 3)
        ACC(u1.x, 4)  ACC(u1.y, 5)  ACC(u1.z, 6)  ACC(u1.w, 7)
        ACC(u2.x, 8)  ACC(u2.y, 9)  ACC(u2.z, 10) ACC(u2.w, 11)
        ACC(u3.x, 12) ACC(u3.y, 13) ACC(u3.z, 14) ACC(u3.w, 15)
#undef ACC
        ushort4 st;
        st.x = f2bf(a0); st.y = f2bf(a1); st.z = f2bf(a2); st.w = f2bf(a3);
        *(ushort4*)vb = st;
        vb += (size_t)NI * CQ;
    }
}

// ---------------------------------------------------------------------------
// Kernel B: DR routing, streaming votes with 1-step register prefetch.
// block = 256 (4 waves) -- THE allocator regime proven in R1 to give a
// ~170-VGPR budget with no spill: LDS 48.3 KB caps blocks/CU at 3, so the
// compiler targets 3 waves/SIMD and stops starving the kernel at 64 VGPRs
// (1024-thread variants in R4-R6 all got 64 and spilled 300-600 MB/chunk).
// lane l: isub = l>>5, c = l&31; lane owns the full 16-q vote row of
// i = (2*wv + isub) + 8*r, r in [0,36). Agreement in-lane (16 FMA);
// softmax = 5 shfl_xor over the 32-lane c-group; logits in LDS
// (addr i*32+c: 2-way bank aliasing = free). ~60 live VGPRs.
// ---------------------------------------------------------------------------
#define UNPACK16(A, B)                                                     \
    const float f0 = bf_lo(A.x), f1 = bf_hi(A.x), f2 = bf_lo(A.y),         \
                f3 = bf_hi(A.y), f4 = bf_lo(A.z), f5 = bf_hi(A.z),         \
                f6 = bf_lo(A.w), f7 = bf_hi(A.w), f8 = bf_lo(B.x),         \
                f9 = bf_hi(B.x), f10 = bf_lo(B.y), f11 = bf_hi(B.y),       \
                f12 = bf_lo(B.z), f13 = bf_hi(B.z), f14 = bf_lo(B.w),      \
                f15 = bf_hi(B.w);

__global__ __launch_bounds__(256) void route_kernel(
    const ushort_t* __restrict__ votes, const float* __restrict__ bias,
    float* __restrict__ out, int nStart)
{
    __shared__ float lg_lds[NI * OC];     // 36 KB logits
    __shared__ float sPart[RWAVES][CQ];   // 8 KB
    __shared__ float s_sh[CQ];
    __shared__ float v_sh[CQ];
    __shared__ float fac_sh[OC];

    const int bn = blockIdx.x;
    const int t = threadIdx.x;
    const int wv = t >> 6;        // 0..3
    const int l = t & 63;
    const int isub = l >> 5;      // 0 / 1
    const int c = l & 31;
    const int iBase = 2 * wv + isub;   // 0..7; lane's i = iBase + 8*r

    const ushort_t* pbase = votes + (size_t)bn * NI * CQ + (size_t)iBase * CQ + c * OP;
    const size_t stepB = (size_t)8 * CQ;   // +8 i-rows per step

    float sa[16];

    // ---- iter 0 sweep: uniform coupling -> s0 = (sum_i votes)/OC + bias
#pragma unroll
    for (int q = 0; q < 16; ++q) sa[q] = 0.f;
    {
        uint4 A = ((const uint4*)pbase)[0];
        uint4 B = ((const uint4*)pbase)[1];
#pragma unroll 4
        for (int r = 0; r < RSTEPS; ++r) {
            uint4 An, Bn;
            if (r + 1 < RSTEPS) {
                const uint4* pn = (const uint4*)(pbase + (size_t)(r + 1) * stepB);
                An = pn[0]; Bn = pn[1];
            }
            UNPACK16(A, B)
            sa[0] += f0;  sa[1] += f1;  sa[2] += f2;  sa[3] += f3;
            sa[4] += f4;  sa[5] += f5;  sa[6] += f6;  sa[7] += f7;
            sa[8] += f8;  sa[9] += f9;  sa[10] += f10; sa[11] += f11;
            sa[12] += f12; sa[13] += f13; sa[14] += f14; sa[15] += f15;
            A = An; B = Bn;
        }
    }
#pragma unroll
    for (int q = 0; q < 16; ++q) sa[q] += __shfl_xor(sa[q], 32);
    if (isub == 0) {
#pragma unroll
        for (int k = 0; k < 4; ++k)
            *(float4*)&sPart[wv][c * 16 + 4 * k] = make_float4(sa[4*k], sa[4*k+1], sa[4*k+2], sa[4*k+3]);
    }

    float vr[16];
#pragma unroll
    for (int it = 0; it <= 2; ++it) {
        // ---- block reduce + squash (produces v_sh)
        __syncthreads();
#pragma unroll
        for (int rep = 0; rep < 2; ++rep) {
            const int k = t + rep * 256;
            float s = (sPart[0][k] + sPart[1][k]) + (sPart[2][k] + sPart[3][k]);
            s_sh[k] = fmaf(s, (it == 0) ? (1.0f / OC) : 1.0f, bias[k]);
        }
        __syncthreads();
        if (t < OC) {
            float sq = 0.f;
#pragma unroll
            for (int q = 0; q < OP; ++q) { const float s = s_sh[t * OP + q]; sq = fmaf(s, s, sq); }
            fac_sh[t] = (sq / (1.0f + sq)) * rsqrtf(sq + EPSQ);   // DR squash factor
        }
        __syncthreads();
#pragma unroll
        for (int rep = 0; rep < 2; ++rep) {
            const int k = t + rep * 256;
            v_sh[k] = s_sh[k] * fac_sh[k >> 4];
        }
        __syncthreads();
        if (it == 2) break;

        // ---- routed sweep (stream + prefetch): agree -> logits -> softmax -> s
#pragma unroll
        for (int k = 0; k < 4; ++k) {
            const float4 v4 = *(const float4*)&v_sh[c * 16 + 4 * k];
            vr[4*k] = v4.x; vr[4*k+1] = v4.y; vr[4*k+2] = v4.z; vr[4*k+3] = v4.w;
        }
#pragma unroll
        for (int q = 0; q < 16; ++q) sa[q] = 0.f;
        uint4 A = ((const uint4*)pbase)[0];
        uint4 B = ((const uint4*)pbase)[1];
#pragma unroll 4
        for (int r = 0; r < RSTEPS; ++r) {
            uint4 An, Bn;
            if (r + 1 < RSTEPS) {
                const uint4* pn = (const uint4*)(pbase + (size_t)(r + 1) * stepB);
                An = pn[0]; Bn = pn[1];
            }
            UNPACK16(A, B)
            float a = f0 * vr[0];
            a = fmaf(f1, vr[1], a);   a = fmaf(f2, vr[2], a);   a = fmaf(f3, vr[3], a);
            a = fmaf(f4, vr[4], a);   a = fmaf(f5, vr[5], a);   a = fmaf(f6, vr[6], a);
            a = fmaf(f7, vr[7], a);   a = fmaf(f8, vr[8], a);   a = fmaf(f9, vr[9], a);
            a = fmaf(f10, vr[10], a); a = fmaf(f11, vr[11], a); a = fmaf(f12, vr[12], a);
            a = fmaf(f13, vr[13], a); a = fmaf(f14, vr[14], a); a = fmaf(f15, vr[15], a);
            const int li = (iBase + 8 * r) * OC + c;
            if (it == 0) lg_lds[li] = a;           // logits after iter 0
            else          a += lg_lds[li];          // accumulated logits
            // softmax over 32 output caps (lane bits 0..4); |a| <= ~2 so the
            // max-subtraction is unnecessary (exp can't overflow)
            const float e = __expf(a);
            float es = e;
            es += __shfl_xor(es, 1);
            es += __shfl_xor(es, 2);
            es += __shfl_xor(es, 4);
            es += __shfl_xor(es, 8);
            es += __shfl_xor(es, 16);
            const float coup = __fdividef(e, es);
            sa[0] = fmaf(coup, f0, sa[0]);   sa[1] = fmaf(coup, f1, sa[1]);
            sa[2] = fmaf(coup, f2, sa[2]);   sa[3] = fmaf(coup, f3, sa[3]);
            sa[4] = fmaf(coup, f4, sa[4]);   sa[5] = fmaf(coup, f5, sa[5]);
            sa[6] = fmaf(coup, f6, sa[6]);   sa[7] = fmaf(coup, f7, sa[7]);
            sa[8] = fmaf(coup, f8, sa[8]);   sa[9] = fmaf(coup, f9, sa[9]);
            sa[10] = fmaf(coup, f10, sa[10]); sa[11] = fmaf(coup, f11, sa[11]);
            sa[12] = fmaf(coup, f12, sa[12]); sa[13] = fmaf(coup, f13, sa[13]);
            sa[14] = fmaf(coup, f14, sa[14]); sa[15] = fmaf(coup, f15, sa[15]);
            A = An; B = Bn;
        }
#pragma unroll
        for (int q = 0; q < 16; ++q) sa[q] += __shfl_xor(sa[q], 32);
        if (isub == 0) {
#pragma unroll
            for (int k = 0; k < 4; ++k)
                *(float4*)&sPart[wv][c * 16 + 4 * k] = make_float4(sa[4*k], sa[4*k+1], sa[4*k+2], sa[4*k+3]);
        }
    }

#pragma unroll
    for (int rep = 0; rep < 2; ++rep) {
        const int k = t + rep * 256;
        out[(size_t)(nStart + bn) * CQ + k] = v_sh[k];
    }
}

// ---------------------------------------------------------------------------
extern "C" void kernel_launch(void* const* d_in, const int* in_sizes, int n_in,
                              void* d_out, int out_size, void* d_ws, size_t ws_size,
                              hipStream_t stream)
{
    const float* x = (const float*)d_in[0];
    const float* Wg = (const float*)d_in[1];
    const float* bias = (const float*)d_in[2];
    float* out = (float*)d_out;
    ushort_t* votes = (ushort_t*)d_ws;

    const size_t perN = (size_t)NI * CQ * sizeof(ushort_t);  // 294912 B per pixel
    size_t fit = ws_size / perN;
    int chunk = (fit >= 576) ? 576 : (int)fit;   // 576 px = 169 MB votes, L3-resident
    if (chunk < 1) chunk = 1;

    for (int start = 0; start < NTOT; start += chunk) {
        const int cnt = (NTOT - start < chunk) ? (NTOT - start) : chunk;
        dim3 gA(NI, (cnt + 63) / 64);
        hipLaunchKernelGGL(votes_kernel, gA, dim3(128), 0, stream, x, Wg, votes, start, cnt);
        hipLaunchKernelGGL(route_kernel, dim3(cnt), dim3(256), 0, stream, votes, bias, out, start);
    }
}